// Round 4
// baseline (56.764 us; speedup 1.0000x reference)
//
#include <hip/hip_runtime.h>
#include <hip/hip_bf16.h>
#include <math.h>

#define EPSF 1e-8f

constexpr int N_OBJ  = 8192;
constexpr int M_SR   = 4096;
constexpr int N_FACE = 2048;

// ---------------- ws layout ----------------
// float4 ptrec[2*N_OBJ] : rec[2p]=(ox,oy,oz,d2), rec[2p+1]=(dx,dy,dz,0)  (256 KB)
// int    gcnt[N_OBJ]    : per-point hit counters                          (32 KB)

__device__ __forceinline__ float rlane(float v, int lane) {
    return __int_as_float(__builtin_amdgcn_readlane(__float_as_int(v), lane));
}

// ================= NN kernel: 4 points/wave, 16/block, grid 512 =================
constexpr int SRTILE = 2048;
constexpr int NN_PPW = 4;
constexpr int NN_PPB = NN_PPW * 4;          // 16
constexpr int NN_NBLK = N_OBJ / NN_PPB;     // 512

__global__ __launch_bounds__(256) void nn_kernel(
    const float* __restrict__ obj, const float* __restrict__ srp,
    float* __restrict__ out, float4* __restrict__ ptrec)
{
    __shared__ float4 s4[SRTILE];
    const int tid  = threadIdx.x;
    const int w    = tid >> 6;
    const int lane = tid & 63;
    const int pbase = blockIdx.x * NN_PPB + w * NN_PPW;

    float ox[NN_PPW], oy[NN_PPW], oz[NN_PPW], oo[NN_PPW], best[NN_PPW];
    int bi[NN_PPW];
#pragma unroll
    for (int q = 0; q < NN_PPW; ++q) {
        int n = pbase + q;
        ox[q] = obj[3 * n]; oy[q] = obj[3 * n + 1]; oz[q] = obj[3 * n + 2];
        oo[q] = ox[q] * ox[q] + oy[q] * oy[q] + oz[q] * oz[q];
        best[q] = 3.4e38f; bi[q] = 0;
    }

    for (int t0 = 0; t0 < M_SR; t0 += SRTILE) {
        __syncthreads();
        for (int i = tid; i < SRTILE; i += 256) {
            float sx = srp[3 * (t0 + i) + 0];
            float sy = srp[3 * (t0 + i) + 1];
            float sz = srp[3 * (t0 + i) + 2];
            s4[i] = make_float4(sx, sy, sz, sx * sx + sy * sy + sz * sz);
        }
        __syncthreads();
        for (int j = 0; j < SRTILE / 64; ++j) {
            int s = j * 64 + lane;
            float4 v = s4[s];
#pragma unroll
            for (int q = 0; q < NN_PPW; ++q) {
                float m = v.w - 2.0f * (ox[q] * v.x + oy[q] * v.y + oz[q] * v.z);
                if (m < best[q]) { best[q] = m; bi[q] = t0 + s; }
            }
        }
    }
    for (int off = 1; off < 64; off <<= 1) {
#pragma unroll
        for (int q = 0; q < NN_PPW; ++q) {
            float od = __shfl_xor(best[q], off);
            int   oi = __shfl_xor(bi[q], off);
            if (od < best[q] || (od == best[q] && oi < bi[q])) { best[q] = od; bi[q] = oi; }
        }
    }
    if (lane == 0) {
#pragma unroll
        for (int q = 0; q < NN_PPW; ++q) {
            int n = pbase + q;
            float d2 = best[q] + oo[q];
            float dx = srp[3 * bi[q]] - ox[q];
            float dy = srp[3 * bi[q] + 1] - oy[q];
            float dz = srp[3 * bi[q] + 2] - oz[q];
            ptrec[2 * n]     = make_float4(ox[q], oy[q], oz[q], d2);
            ptrec[2 * n + 1] = make_float4(dx, dy, dz, 0.0f);
            out[1 + n] = 2.0f / (1.0f + expf(100.0f * sqrtf(d2 + EPSF)));
        }
    }
}

// ====== face kernel: 1 face/lane in regs, 64-pt chunk via readlane, no LDS ======
constexpr int FK_FG    = N_FACE / 256;      // 8 face groups
constexpr int FK_CH    = N_OBJ / 64;        // 128 point chunks
constexpr int FK_NBLK  = FK_FG * FK_CH;     // 1024

__global__ __launch_bounds__(256) void face_kernel(
    const float* __restrict__ verts, const int* __restrict__ faces,
    const float* __restrict__ fnorm, const float4* __restrict__ ptrec,
    int* __restrict__ gcnt)
{
    const int tid  = threadIdx.x;
    const int lane = tid & 63;
    const int fg   = blockIdx.x & (FK_FG - 1);
    const int pc   = blockIdx.x / FK_FG;
    const int f    = fg * 256 + tid;

    // ---- per-lane face constants (registers) ----
    int i0 = faces[3 * f + 0], i1 = faces[3 * f + 1], i2 = faces[3 * f + 2];
    float ax = verts[3 * i0 + 0], ay = verts[3 * i0 + 1], az = verts[3 * i0 + 2];
    float bx = verts[3 * i1 + 0], by = verts[3 * i1 + 1], bz = verts[3 * i1 + 2];
    float cx = verts[3 * i2 + 0], cy = verts[3 * i2 + 1], cz = verts[3 * i2 + 2];
    float fx = fnorm[3 * f + 0], fy = fnorm[3 * f + 1], fz = fnorm[3 * f + 2];
    float nf = fx * ax + fy * ay + fz * az;

    float e0x = bx - ax, e0y = by - ay, e0z = bz - az;
    float g0x = fy * e0z - fz * e0y, g0y = fz * e0x - fx * e0z, g0z = fx * e0y - fy * e0x;
    float h0  = g0x * ax + g0y * ay + g0z * az;
    float e1x = cx - bx, e1y = cy - by, e1z = cz - bz;
    float g1x = fy * e1z - fz * e1y, g1y = fz * e1x - fx * e1z, g1z = fx * e1y - fy * e1x;
    float h1  = g1x * bx + g1y * by + g1z * bz;
    float e2x = ax - cx, e2y = ay - cy, e2z = az - cz;
    float g2x = fy * e2z - fz * e2y, g2y = fz * e2x - fx * e2z, g2z = fx * e2y - fy * e2x;
    float h2  = g2x * cx + g2y * cy + g2z * cz;

    // ---- this block's 64-point chunk, transposed into lane registers ----
    const int pbase = pc * 64;
    float4 r0 = ptrec[2 * (pbase + lane)];
    float4 r1 = ptrec[2 * (pbase + lane) + 1];

    unsigned int cnt = 0;
#pragma unroll 2
    for (int p = 0; p < 64; ++p) {
        float pox = rlane(r0.x, p), poy = rlane(r0.y, p), poz = rlane(r0.z, p);
        float pdx = rlane(r1.x, p), pdy = rlane(r1.y, p), pdz = rlane(r1.z, p);

        float den = fx * pdx + fy * pdy + fz * pdz;
        float num = nf - (fx * pox + fy * poy + fz * poz);
        float Px  = den * pox + num * pdx;
        float Py  = den * poy + num * pdy;
        float Pz  = den * poz + num * pdz;
        bool pos = den >= 0.0f;
        bool ok0 = ((g0x * Px + g0y * Py + g0z * Pz - den * h0) >= 0.0f) == pos;
        bool ok1 = ((g1x * Px + g1y * Py + g1z * Pz - den * h1) >= 0.0f) == pos;
        bool ok2 = ((g2x * Px + g2y * Py + g2z * Pz - den * h2) >= 0.0f) == pos;
        bool tok = (num >= 0.0f) == pos;
        bool aok = fabsf(den) >= EPSF;
        bool hit = ok0 & ok1 & ok2 & tok & aok;

        unsigned long long m = __ballot(hit);
        unsigned int pop = (unsigned int)__popcll(m);
        cnt += (lane == p) ? pop : 0u;      // pop is wave-uniform; lane p keeps point p's count
    }
    atomicAdd(&gcnt[pbase + lane], (int)cnt);
}

// ================= finalize: parity -> pen_dist =================
__global__ __launch_bounds__(1024) void fin_kernel(
    const float4* __restrict__ ptrec, const int* __restrict__ gcnt,
    float* __restrict__ out)
{
    __shared__ float wsum[16];
    const int tid = threadIdx.x;
    float s = 0.0f;
    for (int i = tid; i < N_OBJ; i += 1024)
        if (gcnt[i] & 1) s += ptrec[2 * i].w;
    for (int off = 1; off < 64; off <<= 1) s += __shfl_xor(s, off);
    if ((tid & 63) == 0) wsum[tid >> 6] = s;
    __syncthreads();
    if (tid == 0) {
        float t = 0.0f;
#pragma unroll
        for (int k = 0; k < 16; ++k) t += wsum[k];
        out[0] = sqrtf(t);
    }
}

extern "C" void kernel_launch(void* const* d_in, const int* in_sizes, int n_in,
                              void* d_out, int out_size, void* d_ws, size_t ws_size,
                              hipStream_t stream)
{
    const float* obj   = (const float*)d_in[0];
    const float* srp   = (const float*)d_in[1];
    const float* verts = (const float*)d_in[2];
    const int*   faces = (const int*)d_in[3];
    const float* fnorm = (const float*)d_in[4];
    float*       out   = (float*)d_out;

    float4* ptrec = (float4*)d_ws;
    int*    gcnt  = (int*)((char*)d_ws + 2 * N_OBJ * sizeof(float4));

    (void)hipMemsetAsync(gcnt, 0, N_OBJ * sizeof(int), stream);
    nn_kernel<<<NN_NBLK, 256, 0, stream>>>(obj, srp, out, ptrec);
    face_kernel<<<FK_NBLK, 256, 0, stream>>>(verts, faces, fnorm, ptrec, gcnt);
    fin_kernel<<<1, 1024, 0, stream>>>(ptrec, gcnt, out);
}

// Round 5
// 53.647 us; speedup vs baseline: 1.0581x; 1.0581x over previous
//
#include <hip/hip_runtime.h>
#include <hip/hip_bf16.h>
#include <math.h>

#define EPSF 1e-8f

constexpr int N_OBJ  = 8192;
constexpr int M_SR   = 4096;
constexpr int N_FACE = 2048;

// ---------------- ws layout (no zero-init required anywhere) ----------------
// float4 ptrec[2*N_OBJ]     : rec[2p]=(ox,oy,oz,d2), rec[2p+1]=(dx,dy,dz,0)   (256 KB)
// int    gcnt[8][N_OBJ]     : per-face-group hit counts, plain stores          (256 KB)

__device__ __forceinline__ float rlane(float v, int lane) {
    return __int_as_float(__builtin_amdgcn_readlane(__float_as_int(v), lane));
}

// ================= NN kernel: 4 points/wave, 16/block, grid 512 =================
constexpr int SRTILE = 2048;
constexpr int NN_PPW = 4;
constexpr int NN_PPB = NN_PPW * 4;          // 16
constexpr int NN_NBLK = N_OBJ / NN_PPB;     // 512

__global__ __launch_bounds__(256) void nn_kernel(
    const float* __restrict__ obj, const float* __restrict__ srp,
    float* __restrict__ out, float4* __restrict__ ptrec)
{
    __shared__ float4 s4[SRTILE];
    const int tid  = threadIdx.x;
    const int w    = tid >> 6;
    const int lane = tid & 63;
    const int pbase = blockIdx.x * NN_PPB + w * NN_PPW;

    float ox[NN_PPW], oy[NN_PPW], oz[NN_PPW], oo[NN_PPW], best[NN_PPW];
    int bi[NN_PPW];
#pragma unroll
    for (int q = 0; q < NN_PPW; ++q) {
        int n = pbase + q;
        ox[q] = obj[3 * n]; oy[q] = obj[3 * n + 1]; oz[q] = obj[3 * n + 2];
        oo[q] = ox[q] * ox[q] + oy[q] * oy[q] + oz[q] * oz[q];
        best[q] = 3.4e38f; bi[q] = 0;
    }

    for (int t0 = 0; t0 < M_SR; t0 += SRTILE) {
        __syncthreads();
        for (int i = tid; i < SRTILE; i += 256) {
            float sx = srp[3 * (t0 + i) + 0];
            float sy = srp[3 * (t0 + i) + 1];
            float sz = srp[3 * (t0 + i) + 2];
            s4[i] = make_float4(sx, sy, sz, sx * sx + sy * sy + sz * sz);
        }
        __syncthreads();
        for (int j = 0; j < SRTILE / 64; ++j) {
            int s = j * 64 + lane;
            float4 v = s4[s];
#pragma unroll
            for (int q = 0; q < NN_PPW; ++q) {
                float m = v.w - 2.0f * (ox[q] * v.x + oy[q] * v.y + oz[q] * v.z);
                if (m < best[q]) { best[q] = m; bi[q] = t0 + s; }
            }
        }
    }
    for (int off = 1; off < 64; off <<= 1) {
#pragma unroll
        for (int q = 0; q < NN_PPW; ++q) {
            float od = __shfl_xor(best[q], off);
            int   oi = __shfl_xor(bi[q], off);
            if (od < best[q] || (od == best[q] && oi < bi[q])) { best[q] = od; bi[q] = oi; }
        }
    }
    if (lane == 0) {
#pragma unroll
        for (int q = 0; q < NN_PPW; ++q) {
            int n = pbase + q;
            float d2 = best[q] + oo[q];
            float dx = srp[3 * bi[q]] - ox[q];
            float dy = srp[3 * bi[q] + 1] - oy[q];
            float dz = srp[3 * bi[q] + 2] - oz[q];
            ptrec[2 * n]     = make_float4(ox[q], oy[q], oz[q], d2);
            ptrec[2 * n + 1] = make_float4(dx, dy, dz, 0.0f);
            out[1 + n] = 2.0f / (1.0f + expf(100.0f * sqrtf(d2 + EPSF)));
        }
    }
}

// ====== face kernel: 1 face/lane in regs, 64-pt chunk via readlane, no atomics ======
constexpr int FK_FG    = N_FACE / 256;      // 8 face groups
constexpr int FK_CH    = N_OBJ / 64;        // 128 point chunks
constexpr int FK_NBLK  = FK_FG * FK_CH;     // 1024

__global__ __launch_bounds__(256) void face_kernel(
    const float* __restrict__ verts, const int* __restrict__ faces,
    const float* __restrict__ fnorm, const float4* __restrict__ ptrec,
    int* __restrict__ gcnt)
{
    __shared__ int sc[256];
    const int tid  = threadIdx.x;
    const int w    = tid >> 6;
    const int lane = tid & 63;
    const int fg   = blockIdx.x & (FK_FG - 1);
    const int pc   = blockIdx.x / FK_FG;
    const int f    = fg * 256 + tid;

    // ---- per-lane face constants (registers) ----
    int i0 = faces[3 * f + 0], i1 = faces[3 * f + 1], i2 = faces[3 * f + 2];
    float ax = verts[3 * i0 + 0], ay = verts[3 * i0 + 1], az = verts[3 * i0 + 2];
    float bx = verts[3 * i1 + 0], by = verts[3 * i1 + 1], bz = verts[3 * i1 + 2];
    float cx = verts[3 * i2 + 0], cy = verts[3 * i2 + 1], cz = verts[3 * i2 + 2];
    float fx = fnorm[3 * f + 0], fy = fnorm[3 * f + 1], fz = fnorm[3 * f + 2];
    float nf = fx * ax + fy * ay + fz * az;

    float e0x = bx - ax, e0y = by - ay, e0z = bz - az;
    float g0x = fy * e0z - fz * e0y, g0y = fz * e0x - fx * e0z, g0z = fx * e0y - fy * e0x;
    float h0  = g0x * ax + g0y * ay + g0z * az;
    float e1x = cx - bx, e1y = cy - by, e1z = cz - bz;
    float g1x = fy * e1z - fz * e1y, g1y = fz * e1x - fx * e1z, g1z = fx * e1y - fy * e1x;
    float h1  = g1x * bx + g1y * by + g1z * bz;
    float e2x = ax - cx, e2y = ay - cy, e2z = az - cz;
    float g2x = fy * e2z - fz * e2y, g2y = fz * e2x - fx * e2z, g2z = fx * e2y - fy * e2x;
    float h2  = g2x * cx + g2y * cy + g2z * cz;

    // ---- this block's 64-point chunk, transposed into lane registers ----
    const int pbase = pc * 64;
    float4 r0 = ptrec[2 * (pbase + lane)];
    float4 r1 = ptrec[2 * (pbase + lane) + 1];

    unsigned int cnt = 0;
#pragma unroll 2
    for (int p = 0; p < 64; ++p) {
        float pox = rlane(r0.x, p), poy = rlane(r0.y, p), poz = rlane(r0.z, p);
        float pdx = rlane(r1.x, p), pdy = rlane(r1.y, p), pdz = rlane(r1.z, p);

        float den = fx * pdx + fy * pdy + fz * pdz;
        float num = nf - (fx * pox + fy * poy + fz * poz);
        float Px  = den * pox + num * pdx;
        float Py  = den * poy + num * pdy;
        float Pz  = den * poz + num * pdz;
        bool pos = den >= 0.0f;
        bool ok0 = ((g0x * Px + g0y * Py + g0z * Pz - den * h0) >= 0.0f) == pos;
        bool ok1 = ((g1x * Px + g1y * Py + g1z * Pz - den * h1) >= 0.0f) == pos;
        bool ok2 = ((g2x * Px + g2y * Py + g2z * Pz - den * h2) >= 0.0f) == pos;
        bool tok = (num >= 0.0f) == pos;
        bool aok = fabsf(den) >= EPSF;
        bool hit = ok0 & ok1 & ok2 & tok & aok;

        unsigned long long m = __ballot(hit);
        unsigned int pop = (unsigned int)__popcll(m);
        cnt += (lane == p) ? pop : 0u;      // pop is wave-uniform; lane p keeps point p's count
    }

    // intra-block reduce across the 4 waves, then one plain store per point
    sc[w * 64 + lane] = (int)cnt;
    __syncthreads();
    if (tid < 64) {
        int tot = sc[tid] + sc[64 + tid] + sc[128 + tid] + sc[192 + tid];
        gcnt[fg * N_OBJ + pbase + tid] = tot;   // fully overwritten every call
    }
}

// ================= finalize: parity -> pen_dist =================
__global__ __launch_bounds__(1024) void fin_kernel(
    const float4* __restrict__ ptrec, const int* __restrict__ gcnt,
    float* __restrict__ out)
{
    __shared__ float wsum[16];
    const int tid = threadIdx.x;
    float s = 0.0f;
    for (int i = tid; i < N_OBJ; i += 1024) {
        int tot = 0;
#pragma unroll
        for (int g = 0; g < FK_FG; ++g) tot += gcnt[g * N_OBJ + i];
        if (tot & 1) s += ptrec[2 * i].w;
    }
    for (int off = 1; off < 64; off <<= 1) s += __shfl_xor(s, off);
    if ((tid & 63) == 0) wsum[tid >> 6] = s;
    __syncthreads();
    if (tid == 0) {
        float t = 0.0f;
#pragma unroll
        for (int k = 0; k < 16; ++k) t += wsum[k];
        out[0] = sqrtf(t);
    }
}

extern "C" void kernel_launch(void* const* d_in, const int* in_sizes, int n_in,
                              void* d_out, int out_size, void* d_ws, size_t ws_size,
                              hipStream_t stream)
{
    const float* obj   = (const float*)d_in[0];
    const float* srp   = (const float*)d_in[1];
    const float* verts = (const float*)d_in[2];
    const int*   faces = (const int*)d_in[3];
    const float* fnorm = (const float*)d_in[4];
    float*       out   = (float*)d_out;

    float4* ptrec = (float4*)d_ws;
    int*    gcnt  = (int*)((char*)d_ws + 2 * N_OBJ * sizeof(float4));

    nn_kernel<<<NN_NBLK, 256, 0, stream>>>(obj, srp, out, ptrec);
    face_kernel<<<FK_NBLK, 256, 0, stream>>>(verts, faces, fnorm, ptrec, gcnt);
    fin_kernel<<<1, 1024, 0, stream>>>(ptrec, gcnt, out);
}

// Round 6
// 45.063 us; speedup vs baseline: 1.2596x; 1.1905x over previous
//
#include <hip/hip_runtime.h>
#include <hip/hip_bf16.h>
#include <math.h>

#define EPSF 1e-8f

constexpr int N_OBJ  = 8192;
constexpr int M_SR   = 4096;
constexpr int N_FACE = 2048;

// ---------------- ws layout (no zero-init required anywhere) ----------------
// off 0      : float4 ptrec[2*N_OBJ]   rec[2p]=(ox,oy,oz,d2), rec[2p+1]=(dx,dy,dz,0)  (256 KB)
// off 256K   : float  fd[N_FACE][16]   face constants AoS (64 B/face)                 (128 KB)
// off 384K   : int    gcnt[32][N_OBJ]  per-face-split hit counts                      (1 MB)
// off 1408K  : float  pensum[32]       per-finP-block partial sums
constexpr size_t OFF_FD   = 2 * N_OBJ * sizeof(float4);
constexpr size_t OFF_GCNT = OFF_FD + N_FACE * 16 * sizeof(float);
constexpr size_t OFF_PEN  = OFF_GCNT + 32ull * N_OBJ * sizeof(int);

// ================= face constant setup =================
__global__ __launch_bounds__(256) void face_setup(
    const float* __restrict__ verts, const int* __restrict__ faces,
    const float* __restrict__ fnorm, float* __restrict__ fd)
{
    int f = blockIdx.x * 256 + threadIdx.x;
    if (f >= N_FACE) return;
    int i0 = faces[3 * f + 0], i1 = faces[3 * f + 1], i2 = faces[3 * f + 2];
    float ax = verts[3 * i0 + 0], ay = verts[3 * i0 + 1], az = verts[3 * i0 + 2];
    float bx = verts[3 * i1 + 0], by = verts[3 * i1 + 1], bz = verts[3 * i1 + 2];
    float cx = verts[3 * i2 + 0], cy = verts[3 * i2 + 1], cz = verts[3 * i2 + 2];
    float fx = fnorm[3 * f + 0], fy = fnorm[3 * f + 1], fz = fnorm[3 * f + 2];
    float nf = fx * ax + fy * ay + fz * az;

    float e0x = bx - ax, e0y = by - ay, e0z = bz - az;
    float g0x = fy * e0z - fz * e0y, g0y = fz * e0x - fx * e0z, g0z = fx * e0y - fy * e0x;
    float h0  = g0x * ax + g0y * ay + g0z * az;
    float e1x = cx - bx, e1y = cy - by, e1z = cz - bz;
    float g1x = fy * e1z - fz * e1y, g1y = fz * e1x - fx * e1z, g1z = fx * e1y - fy * e1x;
    float h1  = g1x * bx + g1y * by + g1z * bz;
    float e2x = ax - cx, e2y = ay - cy, e2z = az - cz;
    float g2x = fy * e2z - fz * e2y, g2y = fz * e2x - fx * e2z, g2z = fx * e2y - fy * e2x;
    float h2  = g2x * cx + g2y * cy + g2z * cz;

    float* o = fd + f * 16;
    o[0] = fx;  o[1] = fy;  o[2] = fz;  o[3] = nf;
    o[4] = g0x; o[5] = g0y; o[6] = g0z; o[7] = h0;
    o[8] = g1x; o[9] = g1y; o[10] = g1z; o[11] = h1;
    o[12] = g2x; o[13] = g2y; o[14] = g2z; o[15] = h2;
}

// ================= NN kernel: 2 points/wave, 8/block, grid 1024 =================
constexpr int SRTILE = 2048;
constexpr int NN_PPW = 2;
constexpr int NN_PPB = NN_PPW * 4;          // 8
constexpr int NN_NBLK = N_OBJ / NN_PPB;     // 1024

__global__ __launch_bounds__(256) void nn_kernel(
    const float* __restrict__ obj, const float* __restrict__ srp,
    float* __restrict__ out, float4* __restrict__ ptrec)
{
    __shared__ float4 s4[SRTILE];
    const int tid  = threadIdx.x;
    const int w    = tid >> 6;
    const int lane = tid & 63;
    const int pbase = blockIdx.x * NN_PPB + w * NN_PPW;

    float ox[NN_PPW], oy[NN_PPW], oz[NN_PPW], oo[NN_PPW], best[NN_PPW];
    int bi[NN_PPW];
#pragma unroll
    for (int q = 0; q < NN_PPW; ++q) {
        int n = pbase + q;
        ox[q] = obj[3 * n]; oy[q] = obj[3 * n + 1]; oz[q] = obj[3 * n + 2];
        oo[q] = ox[q] * ox[q] + oy[q] * oy[q] + oz[q] * oz[q];
        best[q] = 3.4e38f; bi[q] = 0;
    }

    for (int t0 = 0; t0 < M_SR; t0 += SRTILE) {
        __syncthreads();
        for (int i = tid; i < SRTILE; i += 256) {
            float sx = srp[3 * (t0 + i) + 0];
            float sy = srp[3 * (t0 + i) + 1];
            float sz = srp[3 * (t0 + i) + 2];
            s4[i] = make_float4(sx, sy, sz, sx * sx + sy * sy + sz * sz);
        }
        __syncthreads();
#pragma unroll 4
        for (int j = 0; j < SRTILE / 64; ++j) {
            int s = j * 64 + lane;
            float4 v = s4[s];
#pragma unroll
            for (int q = 0; q < NN_PPW; ++q) {
                float m = v.w - 2.0f * (ox[q] * v.x + oy[q] * v.y + oz[q] * v.z);
                if (m < best[q]) { best[q] = m; bi[q] = t0 + s; }
            }
        }
    }
    for (int off = 1; off < 64; off <<= 1) {
#pragma unroll
        for (int q = 0; q < NN_PPW; ++q) {
            float od = __shfl_xor(best[q], off);
            int   oi = __shfl_xor(bi[q], off);
            if (od < best[q] || (od == best[q] && oi < bi[q])) { best[q] = od; bi[q] = oi; }
        }
    }
    if (lane == 0) {
#pragma unroll
        for (int q = 0; q < NN_PPW; ++q) {
            int n = pbase + q;
            float d2 = best[q] + oo[q];
            float dx = srp[3 * bi[q]] - ox[q];
            float dy = srp[3 * bi[q] + 1] - oy[q];
            float dz = srp[3 * bi[q] + 2] - oz[q];
            ptrec[2 * n]     = make_float4(ox[q], oy[q], oz[q], d2);
            ptrec[2 * n + 1] = make_float4(dx, dy, dz, 0.0f);
            out[1 + n] = 2.0f / (1.0f + expf(100.0f * sqrtf(d2 + EPSF)));
        }
    }
}

// ====== face kernel: point-per-lane, face constants via scalar loads ======
constexpr int FK_FS   = 32;                  // face splits (64 faces each)
constexpr int FK_PB   = N_OBJ / 256;         // 32 point-blocks (256 points each)
constexpr int FK_NBLK = FK_PB * FK_FS;       // 1024

__global__ __launch_bounds__(256) void face_kernel(
    const float* __restrict__ fd, const float4* __restrict__ ptrec,
    int* __restrict__ gcnt)
{
    const int tid   = threadIdx.x;
    const int fs    = blockIdx.x & (FK_FS - 1);
    const int ptblk = blockIdx.x / FK_FS;
    const int p     = ptblk * 256 + tid;

    // per-lane point record
    float4 r0 = ptrec[2 * p];
    float4 r1 = ptrec[2 * p + 1];
    const float pox = r0.x, poy = r0.y, poz = r0.z;
    const float pdx = r1.x, pdy = r1.y, pdz = r1.z;

    const float* __restrict__ c = fd + (fs * 64) * 16;

    int cnt = 0;
#pragma unroll 4
    for (int j = 0; j < 64; ++j) {
        // wave-uniform -> scalar loads
        const float fx  = c[16 * j + 0],  fy  = c[16 * j + 1];
        const float fz  = c[16 * j + 2],  nf  = c[16 * j + 3];
        const float g0x = c[16 * j + 4],  g0y = c[16 * j + 5];
        const float g0z = c[16 * j + 6],  h0  = c[16 * j + 7];
        const float g1x = c[16 * j + 8],  g1y = c[16 * j + 9];
        const float g1z = c[16 * j + 10], h1  = c[16 * j + 11];
        const float g2x = c[16 * j + 12], g2y = c[16 * j + 13];
        const float g2z = c[16 * j + 14], h2  = c[16 * j + 15];

        float den = fx * pdx + fy * pdy + fz * pdz;
        float num = nf - (fx * pox + fy * poy + fz * poz);
        float Px  = den * pox + num * pdx;
        float Py  = den * poy + num * pdy;
        float Pz  = den * poz + num * pdz;
        bool pos = den >= 0.0f;
        bool ok0 = ((g0x * Px + g0y * Py + g0z * Pz - den * h0) >= 0.0f) == pos;
        bool ok1 = ((g1x * Px + g1y * Py + g1z * Pz - den * h1) >= 0.0f) == pos;
        bool ok2 = ((g2x * Px + g2y * Py + g2z * Pz - den * h2) >= 0.0f) == pos;
        bool tok = (num >= 0.0f) == pos;
        bool aok = fabsf(den) >= EPSF;
        cnt += (ok0 & ok1 & ok2 & tok & aok) ? 1 : 0;
    }
    gcnt[fs * N_OBJ + p] = cnt;     // fully overwritten every call
}

// ================= finalize part 1: parity -> per-block partial =================
__global__ __launch_bounds__(256) void finP_kernel(
    const float4* __restrict__ ptrec, const int* __restrict__ gcnt,
    float* __restrict__ pensum)
{
    __shared__ float sc[4];
    const int tid = threadIdx.x;
    const int p   = blockIdx.x * 256 + tid;
    int tot = 0;
#pragma unroll
    for (int s = 0; s < FK_FS; ++s) tot += gcnt[s * N_OBJ + p];
    float v = (tot & 1) ? ptrec[2 * p].w : 0.0f;
    for (int off = 1; off < 64; off <<= 1) v += __shfl_xor(v, off);
    if ((tid & 63) == 0) sc[tid >> 6] = v;
    __syncthreads();
    if (tid == 0) pensum[blockIdx.x] = sc[0] + sc[1] + sc[2] + sc[3];
}

// ================= finalize part 2: sqrt of 32 partials =================
__global__ __launch_bounds__(64) void fin2_kernel(
    const float* __restrict__ pensum, float* __restrict__ out)
{
    const int lane = threadIdx.x;
    float v = (lane < FK_PB) ? pensum[lane] : 0.0f;
    for (int off = 1; off < 64; off <<= 1) v += __shfl_xor(v, off);
    if (lane == 0) out[0] = sqrtf(v);
}

extern "C" void kernel_launch(void* const* d_in, const int* in_sizes, int n_in,
                              void* d_out, int out_size, void* d_ws, size_t ws_size,
                              hipStream_t stream)
{
    const float* obj   = (const float*)d_in[0];
    const float* srp   = (const float*)d_in[1];
    const float* verts = (const float*)d_in[2];
    const int*   faces = (const int*)d_in[3];
    const float* fnorm = (const float*)d_in[4];
    float*       out   = (float*)d_out;

    float4* ptrec  = (float4*)d_ws;
    float*  fd     = (float*)((char*)d_ws + OFF_FD);
    int*    gcnt   = (int*)((char*)d_ws + OFF_GCNT);
    float*  pensum = (float*)((char*)d_ws + OFF_PEN);

    face_setup<<<(N_FACE + 255) / 256, 256, 0, stream>>>(verts, faces, fnorm, fd);
    nn_kernel<<<NN_NBLK, 256, 0, stream>>>(obj, srp, out, ptrec);
    face_kernel<<<FK_NBLK, 256, 0, stream>>>(fd, ptrec, gcnt);
    finP_kernel<<<FK_PB, 256, 0, stream>>>(ptrec, gcnt, pensum);
    fin2_kernel<<<1, 64, 0, stream>>>(pensum, out);
}